// Round 1
// baseline (10311.698 us; speedup 1.0000x reference)
//
#include <hip/hip_runtime.h>
#include <hip/hip_bf16.h>

// LSTM: T=8192 steps, IN=3000, H=100 (4H=400 gates), torch gate order i,f,g,o.
// Phase 1: xg[T][400] = input_seq @ w_ih^T + (b_ih + b_hh)   (fp32 tiled GEMM)
// Phase 2: single-workgroup sequential scan, w_hh in registers (row per thread)
// Output: scalar = h_last . w_lin + b_lin

#define GBM 128
#define GBN 128
#define GBK 16

__global__ __launch_bounds__(256) void gates_gemm(
    const float* __restrict__ A,    // [T][IN]
    const float* __restrict__ W,    // [FH][IN]
    const float* __restrict__ bih,  // [FH]
    const float* __restrict__ bhh,  // [FH]
    float* __restrict__ XG,         // [T][FH]
    int T, int IN, int FH)
{
    __shared__ __align__(16) float As[GBK][GBM];
    __shared__ __align__(16) float Bs[GBK][GBN];
    const int bm = blockIdx.x * GBM;
    const int bn = blockIdx.y * GBN;
    const int tid = (int)threadIdx.x;
    const int tx = tid & 15, ty = tid >> 4;

    float acc[8][8];
    #pragma unroll
    for (int i = 0; i < 8; ++i)
        #pragma unroll
        for (int j = 0; j < 8; ++j) acc[i][j] = 0.f;

    for (int k0 = 0; k0 < IN; k0 += GBK) {
        __syncthreads();
        // Load tiles: 128 rows x 16 k each = 512 float4 per tile; 2 per thread
        #pragma unroll
        for (int q = 0; q < 2; ++q) {
            int idx = tid + q * 256;          // 0..511
            int row = idx >> 2;               // 0..127
            int kq  = (idx & 3) << 2;         // 0,4,8,12
            int gk  = k0 + kq;
            float4 av = make_float4(0.f, 0.f, 0.f, 0.f);
            float4 bv = make_float4(0.f, 0.f, 0.f, 0.f);
            if (gk < IN) {  // IN % 4 == 0, so gk < IN implies gk+3 < IN
                av = *(const float4*)&A[(size_t)(bm + row) * IN + gk];
                if (bn + row < FH)
                    bv = *(const float4*)&W[(size_t)(bn + row) * IN + gk];
            }
            As[kq + 0][row] = av.x; As[kq + 1][row] = av.y;
            As[kq + 2][row] = av.z; As[kq + 3][row] = av.w;
            Bs[kq + 0][row] = bv.x; Bs[kq + 1][row] = bv.y;
            Bs[kq + 2][row] = bv.z; Bs[kq + 3][row] = bv.w;
        }
        __syncthreads();
        #pragma unroll
        for (int kk = 0; kk < GBK; ++kk) {
            // micro-tile: rows {ty*4+i, 64+ty*4+i}, cols {tx*4+j, 64+tx*4+j}
            float4 a0 = *(const float4*)&As[kk][ty * 4];
            float4 a1 = *(const float4*)&As[kk][64 + ty * 4];
            float4 b0 = *(const float4*)&Bs[kk][tx * 4];
            float4 b1 = *(const float4*)&Bs[kk][64 + tx * 4];
            float am[8] = {a0.x, a0.y, a0.z, a0.w, a1.x, a1.y, a1.z, a1.w};
            float bn_[8] = {b0.x, b0.y, b0.z, b0.w, b1.x, b1.y, b1.z, b1.w};
            #pragma unroll
            for (int i = 0; i < 8; ++i)
                #pragma unroll
                for (int j = 0; j < 8; ++j)
                    acc[i][j] = fmaf(am[i], bn_[j], acc[i][j]);
        }
    }

    #pragma unroll
    for (int i = 0; i < 8; ++i) {
        int r = bm + ((i < 4) ? (ty * 4 + i) : (64 + ty * 4 + (i - 4)));
        #pragma unroll
        for (int j = 0; j < 8; ++j) {
            int cidx = bn + ((j < 4) ? (tx * 4 + j) : (64 + tx * 4 + (j - 4)));
            if (cidx < FH)
                XG[(size_t)r * FH + cidx] = acc[i][j] + bih[cidx] + bhh[cidx];
        }
    }
}

__device__ __forceinline__ float sigmoidf_(float x) {
    return 1.f / (1.f + __expf(-x));
}

// Single-workgroup sequential scan. 512 threads; thread j<400 owns gate-row j
// of w_hh (100 fp32 weights in registers). h broadcast via LDS; c in register
// of threads 0..99.
__global__ __launch_bounds__(512, 1) void lstm_scan(
    const float* __restrict__ XG,    // [T][400]
    const float* __restrict__ Whh,   // [400][100]
    const float* __restrict__ wlin,  // [100]
    const float* __restrict__ blin,  // [1]
    float* __restrict__ out, int T)
{
    const int H = 100, FH = 400;
    __shared__ __align__(16) float h_lds[100];
    __shared__ __align__(16) float g_lds[400];
    const int j = (int)threadIdx.x;

    float4 w4[25];
    if (j < FH) {
        const float4* wr = (const float4*)(Whh + (size_t)j * 100);
        #pragma unroll
        for (int k = 0; k < 25; ++k) w4[k] = wr[k];
    }
    if (j < H) h_lds[j] = 0.f;
    float c = 0.f;
    float xg_cur = (j < FH) ? XG[j] : 0.f;
    __syncthreads();

    for (int t = 0; t < T; ++t) {
        float xg_next = 0.f;
        if (j < FH) {
            if (t + 1 < T) xg_next = XG[(size_t)(t + 1) * FH + j];  // prefetch
            float a0 = 0.f, a1 = 0.f, a2 = 0.f, a3 = 0.f;
            const float4* h4 = (const float4*)h_lds;
            #pragma unroll
            for (int k = 0; k < 25; ++k) {
                float4 hv = h4[k];
                a0 = fmaf(w4[k].x, hv.x, a0);
                a1 = fmaf(w4[k].y, hv.y, a1);
                a2 = fmaf(w4[k].z, hv.z, a2);
                a3 = fmaf(w4[k].w, hv.w, a3);
            }
            g_lds[j] = xg_cur + ((a0 + a1) + (a2 + a3));
        }
        __syncthreads();
        if (j < H) {
            float gi = g_lds[j];
            float gf = g_lds[j + H];
            float gg = g_lds[j + 2 * H];
            float go = g_lds[j + 3 * H];
            float iv = sigmoidf_(gi);
            float fv = sigmoidf_(gf);
            float gv = tanhf(gg);
            float ov = sigmoidf_(go);
            c = fv * c + iv * gv;
            h_lds[j] = ov * tanhf(c);
        }
        __syncthreads();
        xg_cur = xg_next;
    }

    if (j == 0) {
        float acc = blin[0];
        const float4* h4 = (const float4*)h_lds;
        const float4* wl = (const float4*)wlin;
        #pragma unroll
        for (int k = 0; k < 25; ++k) {
            float4 hv = h4[k];
            float4 wv = wl[k];
            acc += hv.x * wv.x + hv.y * wv.y + hv.z * wv.z + hv.w * wv.w;
        }
        out[0] = acc;
    }
}

extern "C" void kernel_launch(void* const* d_in, const int* in_sizes, int n_in,
                              void* d_out, int out_size, void* d_ws, size_t ws_size,
                              hipStream_t stream) {
    const float* input = (const float*)d_in[0];  // [T][IN]
    const float* w_ih  = (const float*)d_in[1];  // [4H][IN]
    const float* w_hh  = (const float*)d_in[2];  // [4H][H]
    const float* b_ih  = (const float*)d_in[3];  // [4H]
    const float* b_hh  = (const float*)d_in[4];  // [4H]
    const float* w_lin = (const float*)d_in[5];  // [H]
    const float* b_lin = (const float*)d_in[6];  // [1]
    float* out = (float*)d_out;

    const int FH = in_sizes[3];            // 400
    const int IN = in_sizes[1] / FH;       // 3000
    const int T  = in_sizes[0] / IN;       // 8192

    float* xg = (float*)d_ws;              // [T][FH] = 13.1 MB

    dim3 grid((T + GBM - 1) / GBM, (FH + GBN - 1) / GBN);
    gates_gemm<<<grid, 256, 0, stream>>>(input, w_ih, b_ih, b_hh, xg, T, IN, FH);
    lstm_scan<<<1, 512, 0, stream>>>(xg, w_hh, w_lin, b_lin, out, T);
}

// Round 2
// 7878.723 us; speedup vs baseline: 1.3088x; 1.3088x over previous
//
#include <hip/hip_runtime.h>
#include <hip/hip_bf16.h>

// LSTM: T=8192, IN=3000, H=100 (4H=400), torch gate order i,f,g,o.
// Phase 1: xg[T][400] = input_seq @ w_ih^T + (b_ih + b_hh)   (fp32 tiled GEMM)
// Phase 2: single-workgroup scan, 128 threads. Thread j<100 owns hidden unit j:
//          holds all 4 w_hh gate rows as packed f16 (v_dot2_f32_f16),
//          h broadcast via f16 LDS (13 ds_read_b128/wave/step), double-buffered,
//          gates stay in registers, 1 barrier/step.

#define GBM 128
#define GBN 128
#define GBK 16

typedef _Float16 h2_t __attribute__((ext_vector_type(2)));
union Chunk { float4 f4; h2_t h2[4]; };

__global__ __launch_bounds__(256) void gates_gemm(
    const float* __restrict__ A,    // [T][IN]
    const float* __restrict__ W,    // [FH][IN]
    const float* __restrict__ bih,  // [FH]
    const float* __restrict__ bhh,  // [FH]
    float* __restrict__ XG,         // [T][FH]
    int T, int IN, int FH)
{
    __shared__ __align__(16) float As[GBK][GBM];
    __shared__ __align__(16) float Bs[GBK][GBN];
    const int bm = blockIdx.x * GBM;
    const int bn = blockIdx.y * GBN;
    const int tid = (int)threadIdx.x;
    const int tx = tid & 15, ty = tid >> 4;

    float acc[8][8];
    #pragma unroll
    for (int i = 0; i < 8; ++i)
        #pragma unroll
        for (int j = 0; j < 8; ++j) acc[i][j] = 0.f;

    for (int k0 = 0; k0 < IN; k0 += GBK) {
        __syncthreads();
        #pragma unroll
        for (int q = 0; q < 2; ++q) {
            int idx = tid + q * 256;
            int row = idx >> 2;
            int kq  = (idx & 3) << 2;
            int gk  = k0 + kq;
            float4 av = make_float4(0.f, 0.f, 0.f, 0.f);
            float4 bv = make_float4(0.f, 0.f, 0.f, 0.f);
            if (gk < IN) {
                av = *(const float4*)&A[(size_t)(bm + row) * IN + gk];
                if (bn + row < FH)
                    bv = *(const float4*)&W[(size_t)(bn + row) * IN + gk];
            }
            As[kq + 0][row] = av.x; As[kq + 1][row] = av.y;
            As[kq + 2][row] = av.z; As[kq + 3][row] = av.w;
            Bs[kq + 0][row] = bv.x; Bs[kq + 1][row] = bv.y;
            Bs[kq + 2][row] = bv.z; Bs[kq + 3][row] = bv.w;
        }
        __syncthreads();
        #pragma unroll
        for (int kk = 0; kk < GBK; ++kk) {
            float4 a0 = *(const float4*)&As[kk][ty * 4];
            float4 a1 = *(const float4*)&As[kk][64 + ty * 4];
            float4 b0 = *(const float4*)&Bs[kk][tx * 4];
            float4 b1 = *(const float4*)&Bs[kk][64 + tx * 4];
            float am[8] = {a0.x, a0.y, a0.z, a0.w, a1.x, a1.y, a1.z, a1.w};
            float bn_[8] = {b0.x, b0.y, b0.z, b0.w, b1.x, b1.y, b1.z, b1.w};
            #pragma unroll
            for (int i = 0; i < 8; ++i)
                #pragma unroll
                for (int j = 0; j < 8; ++j)
                    acc[i][j] = fmaf(am[i], bn_[j], acc[i][j]);
        }
    }

    #pragma unroll
    for (int i = 0; i < 8; ++i) {
        int r = bm + ((i < 4) ? (ty * 4 + i) : (64 + ty * 4 + (i - 4)));
        #pragma unroll
        for (int j = 0; j < 8; ++j) {
            int cidx = bn + ((j < 4) ? (tx * 4 + j) : (64 + tx * 4 + (j - 4)));
            if (cidx < FH)
                XG[(size_t)r * FH + cidx] = acc[i][j] + bih[cidx] + bhh[cidx];
        }
    }
}

__device__ __forceinline__ float sigmoid_fast(float x) {
    return 1.f / (1.f + __expf(-x));
}
__device__ __forceinline__ float tanh_fast(float x) {
    // tanh(x) = 1 - 2/(exp(2x)+1); exp overflow/underflow saturates correctly.
    return 1.f - 2.f / (__expf(2.f * x) + 1.f);
}

__global__ __launch_bounds__(128, 1) void lstm_scan_f16(
    const float* __restrict__ XG,    // [T][400]
    const float* __restrict__ Whh,   // [400][100]
    const float* __restrict__ wlin,  // [100]
    const float* __restrict__ blin,  // [1]
    float* __restrict__ out, int T)
{
    const int H = 100;
    __shared__ __align__(16) _Float16 hbuf[2][104];  // padded 100 -> 104 halves
    __shared__ float hfin[100];
    const int j = (int)threadIdx.x;

    // Thread j < 100 holds gate rows j, j+100, j+200, j+300 as packed f16.
    h2_t w[4][52];
    if (j < H) {
        #pragma unroll
        for (int r = 0; r < 4; ++r) {
            const float2* row = (const float2*)(Whh + (size_t)(j + H * r) * H);
            #pragma unroll
            for (int k = 0; k < 50; ++k) {
                float2 v = row[k];
                w[r][k] = h2_t{(_Float16)v.x, (_Float16)v.y};
            }
            w[r][50] = h2_t{(_Float16)0.f, (_Float16)0.f};
            w[r][51] = h2_t{(_Float16)0.f, (_Float16)0.f};
        }
    }
    if (j < 104) { hbuf[0][j] = (_Float16)0.f; hbuf[1][j] = (_Float16)0.f; }

    float c = 0.f;
    float hlast = 0.f;
    // current-step xg
    float xi = 0.f, xf = 0.f, xg2 = 0.f, xo = 0.f;
    if (j < H) {
        xi = XG[j]; xf = XG[j + 100]; xg2 = XG[j + 200]; xo = XG[j + 300];
    }
    __syncthreads();

    int cur = 0;
    for (int t = 0; t < T; ++t) {
        // prefetch next step's xg (hidden under the dot-product compute)
        float nxi = 0.f, nxf = 0.f, nxg = 0.f, nxo = 0.f;
        if (j < H && t + 1 < T) {
            const float* xr = XG + (size_t)(t + 1) * 400;
            nxi = xr[j]; nxf = xr[j + 100]; nxg = xr[j + 200]; nxo = xr[j + 300];
        }

        float gi = xi, gf = xf, gg = xg2, go = xo;
        const _Float16* hcur = hbuf[cur];
        #pragma unroll
        for (int r = 0; r < 13; ++r) {
            Chunk ch;
            ch.f4 = *(const float4*)&hcur[r * 8];   // one ds_read_b128
            #pragma unroll
            for (int q = 0; q < 4; ++q) {
                h2_t hp = ch.h2[q];
                gi = __builtin_amdgcn_fdot2(w[0][r * 4 + q], hp, gi, false);
                gf = __builtin_amdgcn_fdot2(w[1][r * 4 + q], hp, gf, false);
                gg = __builtin_amdgcn_fdot2(w[2][r * 4 + q], hp, gg, false);
                go = __builtin_amdgcn_fdot2(w[3][r * 4 + q], hp, go, false);
            }
        }

        if (j < H) {
            float iv = sigmoid_fast(gi);
            float fv = sigmoid_fast(gf);
            float gv = tanh_fast(gg);
            float ov = sigmoid_fast(go);
            c = fv * c + iv * gv;
            float h = ov * tanh_fast(c);
            hlast = h;
            hbuf[cur ^ 1][j] = (_Float16)h;
        }
        __syncthreads();
        cur ^= 1;
        xi = nxi; xf = nxf; xg2 = nxg; xo = nxo;
    }

    if (j < H) hfin[j] = hlast * wlin[j];
    __syncthreads();
    if (j == 0) {
        float acc = blin[0];
        for (int k = 0; k < H; ++k) acc += hfin[k];
        out[0] = acc;
    }
}

extern "C" void kernel_launch(void* const* d_in, const int* in_sizes, int n_in,
                              void* d_out, int out_size, void* d_ws, size_t ws_size,
                              hipStream_t stream) {
    const float* input = (const float*)d_in[0];  // [T][IN]
    const float* w_ih  = (const float*)d_in[1];  // [4H][IN]
    const float* w_hh  = (const float*)d_in[2];  // [4H][H]
    const float* b_ih  = (const float*)d_in[3];  // [4H]
    const float* b_hh  = (const float*)d_in[4];  // [4H]
    const float* w_lin = (const float*)d_in[5];  // [H]
    const float* b_lin = (const float*)d_in[6];  // [1]
    float* out = (float*)d_out;

    const int FH = in_sizes[3];            // 400
    const int IN = in_sizes[1] / FH;       // 3000
    const int T  = in_sizes[0] / IN;       // 8192

    float* xg = (float*)d_ws;              // [T][FH] = 13.1 MB

    dim3 grid((T + GBM - 1) / GBM, (FH + GBN - 1) / GBN);
    gates_gemm<<<grid, 256, 0, stream>>>(input, w_ih, b_ih, b_hh, xg, T, IN, FH);
    lstm_scan_f16<<<1, 128, 0, stream>>>(xg, w_hh, w_lin, b_lin, out, T);
}

// Round 3
// 7447.885 us; speedup vs baseline: 1.3845x; 1.0578x over previous
//
#include <hip/hip_runtime.h>
#include <hip/hip_bf16.h>

// LSTM: T=8192, IN=3000, H=100 (4H=400), torch gate order i,f,g,o.
// Phase 1: xg[T][400] = input_seq @ w_ih^T + (b_ih + b_hh)   (fp32 tiled GEMM)
// Phase 2: single-workgroup scan, 256 threads / 4 waves (1 per SIMD).
//   Group 0 (waves 0-1): unit u = tid   (<100), gate rows u (i), u+100 (f)
//   Group 1 (waves 2-3): unit u = tid-128 (<100), gate rows u+200 (g), u+300 (o)
//   Per-thread weights: 2 rows x 52 packed f16 = 104 VGPRs (register-resident;
//   round-2's 208-VGPR layout spilled to scratch at VGPR_Count=140).
//   h broadcast via f16 LDS double buffer; group 1 posts tanh(g)/sig(o) via LDS;
//   XG prefetched 2 steps ahead to cover HBM latency. 2 barriers/step.

#define GBM 128
#define GBN 128
#define GBK 16

typedef _Float16 h2_t __attribute__((ext_vector_type(2)));
union Chunk { float4 f4; h2_t h2[4]; };

__global__ __launch_bounds__(256) void gates_gemm(
    const float* __restrict__ A,    // [T][IN]
    const float* __restrict__ W,    // [FH][IN]
    const float* __restrict__ bih,  // [FH]
    const float* __restrict__ bhh,  // [FH]
    float* __restrict__ XG,         // [T][FH]
    int T, int IN, int FH)
{
    __shared__ __align__(16) float As[GBK][GBM];
    __shared__ __align__(16) float Bs[GBK][GBN];
    const int bm = blockIdx.x * GBM;
    const int bn = blockIdx.y * GBN;
    const int tid = (int)threadIdx.x;
    const int tx = tid & 15, ty = tid >> 4;

    float acc[8][8];
    #pragma unroll
    for (int i = 0; i < 8; ++i)
        #pragma unroll
        for (int j = 0; j < 8; ++j) acc[i][j] = 0.f;

    for (int k0 = 0; k0 < IN; k0 += GBK) {
        __syncthreads();
        #pragma unroll
        for (int q = 0; q < 2; ++q) {
            int idx = tid + q * 256;
            int row = idx >> 2;
            int kq  = (idx & 3) << 2;
            int gk  = k0 + kq;
            float4 av = make_float4(0.f, 0.f, 0.f, 0.f);
            float4 bv = make_float4(0.f, 0.f, 0.f, 0.f);
            if (gk < IN) {
                av = *(const float4*)&A[(size_t)(bm + row) * IN + gk];
                if (bn + row < FH)
                    bv = *(const float4*)&W[(size_t)(bn + row) * IN + gk];
            }
            As[kq + 0][row] = av.x; As[kq + 1][row] = av.y;
            As[kq + 2][row] = av.z; As[kq + 3][row] = av.w;
            Bs[kq + 0][row] = bv.x; Bs[kq + 1][row] = bv.y;
            Bs[kq + 2][row] = bv.z; Bs[kq + 3][row] = bv.w;
        }
        __syncthreads();
        #pragma unroll
        for (int kk = 0; kk < GBK; ++kk) {
            float4 a0 = *(const float4*)&As[kk][ty * 4];
            float4 a1 = *(const float4*)&As[kk][64 + ty * 4];
            float4 b0 = *(const float4*)&Bs[kk][tx * 4];
            float4 b1 = *(const float4*)&Bs[kk][64 + tx * 4];
            float am[8] = {a0.x, a0.y, a0.z, a0.w, a1.x, a1.y, a1.z, a1.w};
            float bn_[8] = {b0.x, b0.y, b0.z, b0.w, b1.x, b1.y, b1.z, b1.w};
            #pragma unroll
            for (int i = 0; i < 8; ++i)
                #pragma unroll
                for (int j = 0; j < 8; ++j)
                    acc[i][j] = fmaf(am[i], bn_[j], acc[i][j]);
        }
    }

    #pragma unroll
    for (int i = 0; i < 8; ++i) {
        int r = bm + ((i < 4) ? (ty * 4 + i) : (64 + ty * 4 + (i - 4)));
        #pragma unroll
        for (int j = 0; j < 8; ++j) {
            int cidx = bn + ((j < 4) ? (tx * 4 + j) : (64 + tx * 4 + (j - 4)));
            if (cidx < FH)
                XG[(size_t)r * FH + cidx] = acc[i][j] + bih[cidx] + bhh[cidx];
        }
    }
}

__device__ __forceinline__ float sigmoid_fast(float x) {
    return 1.f / (1.f + __expf(-x));
}
__device__ __forceinline__ float tanh_fast(float x) {
    // tanh(x) = 1 - 2/(exp(2x)+1); exp saturation gives correct +-1 limits.
    return 1.f - 2.f / (__expf(2.f * x) + 1.f);
}

__global__ __launch_bounds__(256, 1) void lstm_scan2(
    const float* __restrict__ XG,    // [T][400]
    const float* __restrict__ Whh,   // [400][100]
    const float* __restrict__ wlin,  // [100]
    const float* __restrict__ blin,  // [1]
    float* __restrict__ out, int T)
{
    const int H = 100;
    __shared__ __align__(16) _Float16 hbuf[2][104];  // h, padded to 104 halves
    __shared__ float gbuf[2][100];                   // tanh(g), sigmoid(o)
    __shared__ float hfin[100];
    const int j  = (int)threadIdx.x;
    const int wv = j >> 7;          // 0: gates i,f   1: gates g,o
    const int u  = j & 127;         // unit index within group
    const bool active = u < H;

    // ---- load 2 gate rows as packed f16 (52 h2 each, incl. zero pad) ----
    h2_t w0[52], w1[52];
    if (active) {
        const int r0 = u + (wv ? 200 : 0);
        const int r1 = u + (wv ? 300 : 100);
        const float4* p0 = (const float4*)(Whh + (size_t)r0 * H);  // 400B rows, 16B aligned
        const float4* p1 = (const float4*)(Whh + (size_t)r1 * H);
        #pragma unroll
        for (int k = 0; k < 25; ++k) {
            float4 a = p0[k], b = p1[k];
            w0[2 * k]     = h2_t{(_Float16)a.x, (_Float16)a.y};
            w0[2 * k + 1] = h2_t{(_Float16)a.z, (_Float16)a.w};
            w1[2 * k]     = h2_t{(_Float16)b.x, (_Float16)b.y};
            w1[2 * k + 1] = h2_t{(_Float16)b.z, (_Float16)b.w};
        }
        w0[50] = h2_t{(_Float16)0.f, (_Float16)0.f};
        w0[51] = h2_t{(_Float16)0.f, (_Float16)0.f};
        w1[50] = h2_t{(_Float16)0.f, (_Float16)0.f};
        w1[51] = h2_t{(_Float16)0.f, (_Float16)0.f};
    }
    if (j < 104) { hbuf[0][j] = (_Float16)0.f; hbuf[1][j] = (_Float16)0.f; }

    // ---- depth-2 xg prefetch pipeline ----
    const int o0 = (wv ? 200 : 0) + u;
    const int o1 = (wv ? 300 : 100) + u;
    float x0 = 0.f, x1 = 0.f, p0v = 0.f, p1v = 0.f;
    if (active) {
        x0 = XG[o0]; x1 = XG[o1];
        if (T > 1) { p0v = XG[400 + o0]; p1v = XG[400 + o1]; }
    }

    float c = 0.f, hlast = 0.f;
    __syncthreads();

    int cur = 0;
    for (int t = 0; t < T; ++t) {
        // prefetch xg row t+2 (consumed 2 steps from now)
        float n0 = 0.f, n1 = 0.f;
        if (active && t + 2 < T) {
            const float* xr = XG + (size_t)(t + 2) * 400;
            n0 = xr[o0]; n1 = xr[o1];
        }

        float g0 = x0, g1 = x1;
        const _Float16* hc = hbuf[cur];
        #pragma unroll
        for (int r = 0; r < 13; ++r) {
            Chunk ch;
            ch.f4 = *(const float4*)&hc[r * 8];     // one ds_read_b128
            #pragma unroll
            for (int q = 0; q < 4; ++q) {
                h2_t hp = ch.h2[q];
                g0 = __builtin_amdgcn_fdot2(w0[r * 4 + q], hp, g0, false);
                g1 = __builtin_amdgcn_fdot2(w1[r * 4 + q], hp, g1, false);
            }
        }

        if (active && wv) {               // group 1: finish g,o nonlinearity
            gbuf[0][u] = tanh_fast(g0);
            gbuf[1][u] = sigmoid_fast(g1);
        }
        __syncthreads();
        if (active && !wv) {              // group 0: cell update
            float iv = sigmoid_fast(g0);
            float fv = sigmoid_fast(g1);
            float gv = gbuf[0][u];
            float ov = gbuf[1][u];
            c = fv * c + iv * gv;
            float h = ov * tanh_fast(c);
            hlast = h;
            hbuf[cur ^ 1][u] = (_Float16)h;
        }
        __syncthreads();
        cur ^= 1;
        x0 = p0v; x1 = p1v; p0v = n0; p1v = n1;
    }

    if (active && !wv) hfin[u] = hlast * wlin[u];
    __syncthreads();
    if (j == 0) {
        float acc = blin[0];
        for (int k = 0; k < H; ++k) acc += hfin[k];
        out[0] = acc;
    }
}

extern "C" void kernel_launch(void* const* d_in, const int* in_sizes, int n_in,
                              void* d_out, int out_size, void* d_ws, size_t ws_size,
                              hipStream_t stream) {
    const float* input = (const float*)d_in[0];  // [T][IN]
    const float* w_ih  = (const float*)d_in[1];  // [4H][IN]
    const float* w_hh  = (const float*)d_in[2];  // [4H][H]
    const float* b_ih  = (const float*)d_in[3];  // [4H]
    const float* b_hh  = (const float*)d_in[4];  // [4H]
    const float* w_lin = (const float*)d_in[5];  // [H]
    const float* b_lin = (const float*)d_in[6];  // [1]
    float* out = (float*)d_out;

    const int FH = in_sizes[3];            // 400
    const int IN = in_sizes[1] / FH;       // 3000
    const int T  = in_sizes[0] / IN;       // 8192

    float* xg = (float*)d_ws;              // [T][FH] = 13.1 MB

    dim3 grid((T + GBM - 1) / GBM, (FH + GBN - 1) / GBN);
    gates_gemm<<<grid, 256, 0, stream>>>(input, w_ih, b_ih, b_hh, xg, T, IN, FH);
    lstm_scan2<<<1, 256, 0, stream>>>(xg, w_hh, w_lin, b_lin, out, T);
}

// Round 4
// 5825.049 us; speedup vs baseline: 1.7702x; 1.2786x over previous
//
#include <hip/hip_runtime.h>
#include <hip/hip_bf16.h>

// LSTM: T=8192, IN=3000, H=100 (4H=400), torch gate order i,f,g,o.
// Phase 1: xg[T][400] = input_seq @ w_ih^T + (b_ih + b_hh)   (fp32 tiled GEMM)
// Phase 2: single-workgroup scan, 256 threads / 4 waves.
//   Group 0 (tid<128): unit u, gate rows u (i), u+100 (f)
//   Group 1 (tid>=128): unit u, gate rows u+200 (g), u+300 (o)
//   KEY FIX vs round 3: all per-thread weight-array accesses are SOURCE-level
//   unrolled with literal indices (macros). SROA runs before loop unrolling,
//   so runtime-indexed arrays went to scratch (VGPR_Count=104 == no weights
//   in regs; ~2000 cyc/step of scratch reloads). Now every GEP is constant.

#define GBM 128
#define GBN 128
#define GBK 16

typedef _Float16 h2_t __attribute__((ext_vector_type(2)));

__global__ __launch_bounds__(256) void gates_gemm(
    const float* __restrict__ A,    // [T][IN]
    const float* __restrict__ W,    // [FH][IN]
    const float* __restrict__ bih,  // [FH]
    const float* __restrict__ bhh,  // [FH]
    float* __restrict__ XG,         // [T][FH]
    int T, int IN, int FH)
{
    __shared__ __align__(16) float As[GBK][GBM];
    __shared__ __align__(16) float Bs[GBK][GBN];
    const int bm = blockIdx.x * GBM;
    const int bn = blockIdx.y * GBN;
    const int tid = (int)threadIdx.x;
    const int tx = tid & 15, ty = tid >> 4;

    float acc[8][8];
    #pragma unroll
    for (int i = 0; i < 8; ++i)
        #pragma unroll
        for (int j = 0; j < 8; ++j) acc[i][j] = 0.f;

    for (int k0 = 0; k0 < IN; k0 += GBK) {
        __syncthreads();
        #pragma unroll
        for (int q = 0; q < 2; ++q) {
            int idx = tid + q * 256;
            int row = idx >> 2;
            int kq  = (idx & 3) << 2;
            int gk  = k0 + kq;
            float4 av = make_float4(0.f, 0.f, 0.f, 0.f);
            float4 bv = make_float4(0.f, 0.f, 0.f, 0.f);
            if (gk < IN) {
                av = *(const float4*)&A[(size_t)(bm + row) * IN + gk];
                if (bn + row < FH)
                    bv = *(const float4*)&W[(size_t)(bn + row) * IN + gk];
            }
            As[kq + 0][row] = av.x; As[kq + 1][row] = av.y;
            As[kq + 2][row] = av.z; As[kq + 3][row] = av.w;
            Bs[kq + 0][row] = bv.x; Bs[kq + 1][row] = bv.y;
            Bs[kq + 2][row] = bv.z; Bs[kq + 3][row] = bv.w;
        }
        __syncthreads();
        #pragma unroll
        for (int kk = 0; kk < GBK; ++kk) {
            float4 a0 = *(const float4*)&As[kk][ty * 4];
            float4 a1 = *(const float4*)&As[kk][64 + ty * 4];
            float4 b0 = *(const float4*)&Bs[kk][tx * 4];
            float4 b1 = *(const float4*)&Bs[kk][64 + tx * 4];
            float am[8] = {a0.x, a0.y, a0.z, a0.w, a1.x, a1.y, a1.z, a1.w};
            float bn_[8] = {b0.x, b0.y, b0.z, b0.w, b1.x, b1.y, b1.z, b1.w};
            #pragma unroll
            for (int i = 0; i < 8; ++i)
                #pragma unroll
                for (int j = 0; j < 8; ++j)
                    acc[i][j] = fmaf(am[i], bn_[j], acc[i][j]);
        }
    }

    #pragma unroll
    for (int i = 0; i < 8; ++i) {
        int r = bm + ((i < 4) ? (ty * 4 + i) : (64 + ty * 4 + (i - 4)));
        #pragma unroll
        for (int j = 0; j < 8; ++j) {
            int cidx = bn + ((j < 4) ? (tx * 4 + j) : (64 + tx * 4 + (j - 4)));
            if (cidx < FH)
                XG[(size_t)r * FH + cidx] = acc[i][j] + bih[cidx] + bhh[cidx];
        }
    }
}

__device__ __forceinline__ float sigmoid_fast(float x) {
    return 1.f / (1.f + __expf(-x));
}
__device__ __forceinline__ float tanh_fast(float x) {
    // tanh(x) = 1 - 2/(exp(2x)+1); exp saturation gives correct +-1 limits.
    return 1.f - 2.f / (__expf(2.f * x) + 1.f);
}

__global__ __launch_bounds__(256, 1) void lstm_scan3(
    const float* __restrict__ XG,    // [T][400]
    const float* __restrict__ Whh,   // [400][100]
    const float* __restrict__ wlin,  // [100]
    const float* __restrict__ blin,  // [1]
    float* __restrict__ out, int T)
{
    const int H = 100;
    __shared__ __align__(16) _Float16 hbuf[2][104];  // 104*2B = 208B rows (16B mult)
    __shared__ float gbuf[2][100];                   // tanh(g), sigmoid(o)
    __shared__ float hfin[100];
    const int j  = (int)threadIdx.x;
    const int wv = j >> 7;          // 0: gates i,f   1: gates g,o
    const int u  = j & 127;
    const bool active = u < H;
    const int uc = active ? u : (H - 1);   // clamp so ALL threads load valid rows

    const float4* p0 = (const float4*)(Whh + (size_t)(uc + (wv ? 200 : 0)) * H);
    const float4* p1 = (const float4*)(Whh + (size_t)(uc + (wv ? 300 : 100)) * H);

    // ---- per-thread weights: 2 rows x 52 packed f16. ALL indices literal. ----
    h2_t w0[52], w1[52];
#define LOADW(k) { \
    float4 a = p0[k]; float4 b = p1[k]; \
    w0[2*(k)]   = h2_t{(_Float16)a.x, (_Float16)a.y}; \
    w0[2*(k)+1] = h2_t{(_Float16)a.z, (_Float16)a.w}; \
    w1[2*(k)]   = h2_t{(_Float16)b.x, (_Float16)b.y}; \
    w1[2*(k)+1] = h2_t{(_Float16)b.z, (_Float16)b.w}; }
    LOADW(0)  LOADW(1)  LOADW(2)  LOADW(3)  LOADW(4)
    LOADW(5)  LOADW(6)  LOADW(7)  LOADW(8)  LOADW(9)
    LOADW(10) LOADW(11) LOADW(12) LOADW(13) LOADW(14)
    LOADW(15) LOADW(16) LOADW(17) LOADW(18) LOADW(19)
    LOADW(20) LOADW(21) LOADW(22) LOADW(23) LOADW(24)
#undef LOADW
    {
        h2_t z = h2_t{(_Float16)0.f, (_Float16)0.f};
        w0[50] = z; w0[51] = z; w1[50] = z; w1[51] = z;
    }

    if (j < 104) { hbuf[0][j] = (_Float16)0.f; hbuf[1][j] = (_Float16)0.f; }

    // ---- depth-2 xg prefetch pipeline ----
    const int o0 = (wv ? 200 : 0) + u;
    const int o1 = (wv ? 300 : 100) + u;
    float x0 = 0.f, x1 = 0.f, p0v = 0.f, p1v = 0.f;
    if (active) {
        x0 = XG[o0]; x1 = XG[o1];
        if (T > 1) { p0v = XG[400 + o0]; p1v = XG[400 + o1]; }
    }

    float c = 0.f, hlast = 0.f;
    __syncthreads();

    int cur = 0;
    for (int t = 0; t < T; ++t) {
        float n0 = 0.f, n1 = 0.f;
        if (active && t + 2 < T) {
            const float* xr = XG + (size_t)(t + 2) * 400;
            n0 = xr[o0]; n1 = xr[o1];
        }

        float g0 = x0, g1 = x1;
        const _Float16* hc = hbuf[cur];
#define DOT4(r) { \
    float4 hv = *(const float4*)(hc + (r) * 8); \
    h2_t ha = __builtin_bit_cast(h2_t, hv.x); \
    h2_t hb = __builtin_bit_cast(h2_t, hv.y); \
    h2_t hcc = __builtin_bit_cast(h2_t, hv.z); \
    h2_t hd = __builtin_bit_cast(h2_t, hv.w); \
    g0 = __builtin_amdgcn_fdot2(w0[4*(r)+0], ha,  g0, false); \
    g1 = __builtin_amdgcn_fdot2(w1[4*(r)+0], ha,  g1, false); \
    g0 = __builtin_amdgcn_fdot2(w0[4*(r)+1], hb,  g0, false); \
    g1 = __builtin_amdgcn_fdot2(w1[4*(r)+1], hb,  g1, false); \
    g0 = __builtin_amdgcn_fdot2(w0[4*(r)+2], hcc, g0, false); \
    g1 = __builtin_amdgcn_fdot2(w1[4*(r)+2], hcc, g1, false); \
    g0 = __builtin_amdgcn_fdot2(w0[4*(r)+3], hd,  g0, false); \
    g1 = __builtin_amdgcn_fdot2(w1[4*(r)+3], hd,  g1, false); }
        DOT4(0)  DOT4(1)  DOT4(2)  DOT4(3)  DOT4(4)  DOT4(5)  DOT4(6)
        DOT4(7)  DOT4(8)  DOT4(9)  DOT4(10) DOT4(11) DOT4(12)
#undef DOT4

        if (active && wv) {               // group 1: finish g,o nonlinearity
            gbuf[0][u] = tanh_fast(g0);
            gbuf[1][u] = sigmoid_fast(g1);
        }
        __syncthreads();
        if (active && !wv) {              // group 0: cell update
            float iv = sigmoid_fast(g0);
            float fv = sigmoid_fast(g1);
            float gv = gbuf[0][u];
            float ov = gbuf[1][u];
            c = fv * c + iv * gv;
            float h = ov * tanh_fast(c);
            hlast = h;
            hbuf[cur ^ 1][u] = (_Float16)h;
        }
        __syncthreads();
        cur ^= 1;
        x0 = p0v; x1 = p1v; p0v = n0; p1v = n1;
    }

    if (active && !wv) hfin[u] = hlast * wlin[u];
    __syncthreads();
    if (j == 0) {
        float acc = blin[0];
        for (int k = 0; k < H; ++k) acc += hfin[k];
        out[0] = acc;
    }
}

extern "C" void kernel_launch(void* const* d_in, const int* in_sizes, int n_in,
                              void* d_out, int out_size, void* d_ws, size_t ws_size,
                              hipStream_t stream) {
    const float* input = (const float*)d_in[0];  // [T][IN]
    const float* w_ih  = (const float*)d_in[1];  // [4H][IN]
    const float* w_hh  = (const float*)d_in[2];  // [4H][H]
    const float* b_ih  = (const float*)d_in[3];  // [4H]
    const float* b_hh  = (const float*)d_in[4];  // [4H]
    const float* w_lin = (const float*)d_in[5];  // [H]
    const float* b_lin = (const float*)d_in[6];  // [1]
    float* out = (float*)d_out;

    const int FH = in_sizes[3];            // 400
    const int IN = in_sizes[1] / FH;       // 3000
    const int T  = in_sizes[0] / IN;       // 8192

    float* xg = (float*)d_ws;              // [T][FH] = 13.1 MB

    dim3 grid((T + GBM - 1) / GBM, (FH + GBN - 1) / GBN);
    gates_gemm<<<grid, 256, 0, stream>>>(input, w_ih, b_ih, b_hh, xg, T, IN, FH);
    lstm_scan3<<<1, 256, 0, stream>>>(xg, w_hh, w_lin, b_lin, out, T);
}